// Round 10
// baseline (351.644 us; speedup 1.0000x reference)
//
#include <hip/hip_runtime.h>
#include <math.h>

// Problem constants
#define BATCH 32
#define H 512
#define W 512
#define OUTD 502          // 512 - 11 + 1
#define WS 11
#define STRIP 32          // output rows per block
#define INROWS 42         // STRIP + WS - 1 input rows per strip
#define WPAD 80           // per-wave LDS width in float2 units: 64 + 10 halo + pad

#define C1F 6.5025f       // (0.01*255)^2
#define C2F 58.5225f      // (0.03*255)^2
#define N_OUT_TOTAL 8064128.0   // 32 * 502 * 502

struct GW { float g[WS]; };
struct F3 { float x, y, z; };   // 12-byte RGB pixel load
typedef float v2f __attribute__((ext_vector_type(2)));

// ROUND-18: kill the per-step waitcnt drain.
// r17 post-mortem: VALU fell 30% (VALUBusy 36.6->25.8) but wall was
// FLAT (109->108 us) — wall is invariant to instruction count; all 4
// waves/SIMD stall ~74% of each ~6.2k-cycle step on memory. Diagnosis:
// the asm("" ::: "memory") fence is a may-access-all-memory inst at MIR
// level, and the AMDGPU waitcnt inserter conservatively emits
// s_waitcnt vmcnt(0) lgkmcnt(0) before it -> FULL drain of the
// prefetched global loads EVERY row-step. MLP capped at 4 loads/wave/
// step; per-CU step traffic ~12 KB at the measured 1.2 TB/s (~2 B/cyc/
// CU) = ~6.1k cyc/step — exactly the observed step time. We were
// running at drain-rate, not stream-rate.
// Fix: the correctness requirement is only "DS ops keep program order
// across steps" (HW runs DS in wave order). The targeted tool is
// VOLATILE LDS accesses: volatile memops are never reordered against
// each other (IR and MIR) and trigger NO conservative waitcnt
// insertion — global loads float across steps again. Fence REMOVED;
// every sbuf access goes through a volatile pointer. One variable vs
// r17. Tripwire: absmax must stay ~0; a ~0.1-class error means
// volatile ordering is insufficient and the fence returns.
// Everything else = r17 verbatim (proven: absmax 0.0, 120 VGPR):
//   * (s,d) packed transform: LDS holds (a+c, a-c) float2/column; per
//     tap 1 ds_read_b64 + 3 packed-f32 ops; unpack at the epilogue via
//     mu1=(S+D)/2 etc. Ring = 11 x 2 x v2f.
//   * NO occupancy attributes (r12/r14: both knobs => 64 VGPR + 300-420
//     MB scratch spill). Plain launch_bounds(256).
//   * rolled 2-chunk output loop + 10-row tail, ring zero-init,
//     1-row-ahead raw RGB prefetch, luma as 3 FMAs, rcp divide, f32
//     accumulator, 12-byte RGB struct loads.

__device__ __forceinline__ float luma3(float r, float g, float b) {
    // y = ((x+1)*127.5) dot w / 256 + 16  ==  x dot W + K, all f32-folded
    constexpr float W0 = 127.5f * 65.738f  / 256.f;
    constexpr float W1 = 127.5f * 129.057f / 256.f;
    constexpr float W2 = 127.5f * 25.064f  / 256.f;
    constexpr float K0 = 127.5f * 65.738f  / 256.f
                       + 127.5f * 129.057f / 256.f
                       + 127.5f * 25.064f  / 256.f + 16.f;
    return fmaf(r, W0, fmaf(g, W1, fmaf(b, W2, K0)));
}

// Streaming SSIM, one thread per output column, 32-row strip per block,
// wave-private LDS (no barriers, no fences in the row loop; ordering of
// the cross-lane LDS traffic via volatile access).
__global__ __launch_bounds__(256) void ssim_stream_kernel(
    const float* __restrict__ img1, const float* __restrict__ img2,
    double* __restrict__ acc_out, GW wv)
{
    // parity x wave x column, packed (s, d) = (a+c, a-c)
    __shared__ v2f sbuf[2][4][WPAD];
    __shared__ double wsum[4];

    const int t    = threadIdx.x;
    const int lane = t & 63;
    const int wvid = t >> 6;
    const int cw = blockIdx.x * 256 + wvid * 64;  // wave's first column
    const int ox = cw + lane;                     // owned output column
    const int r0 = blockIdx.y * STRIP;
    const int b  = blockIdx.z;

    const bool colok = (ox < OUTD);
    const bool halo  = (lane < 10) && ((cw + 64 + lane) < W);
    const size_t imgbase = (size_t)b * (H * W * 3) + (size_t)r0 * (W * 3);
    const int colA = (cw + lane) * 3;             // main col (always < W)
    const int colB = (cw + 64 + lane) * 3;        // halo col

    // Volatile views of the wave's LDS plane: all cross-lane-hazardous
    // DS ops go through these -> program order preserved, no waitcnt
    // conservatism (unlike the asm memory-clobber fence).
    volatile v2f* const sb0 = &sbuf[0][wvid][0];
    volatile v2f* const sb1 = &sbuf[1][wvid][0];

    // Raw RGB pipeline registers: c* = row iy+1 (ready), n* = row iy+2 (in flight)
    float cA0, cA1, cA2, cB0, cB1, cB2, cC0, cC1, cC2, cD0, cD1, cD2;
    float nA0, nA1, nA2, nB0, nB1, nB2, nC0, nC1, nC2, nD0, nD1, nD2;

// Issue raw loads for strip row IY into 12 named registers (NO conversion
// here — keeping load->use distance at one full row step).
#define LOAD_RAW(IY, A0,A1,A2, B0,B1,B2, C0,C1v,C2v, D0,D1,D2)            \
    {                                                                     \
        A0=A1=A2=B0=B1=B2=C0=C1v=C2v=D0=D1=D2 = 0.f;                      \
        if ((IY) < INROWS && (r0 + (IY)) < H) {                           \
            const float* _q1 = img1 + imgbase + (size_t)((IY) * (W * 3)); \
            const float* _q2 = img2 + imgbase + (size_t)((IY) * (W * 3)); \
            const F3 _pa = *reinterpret_cast<const F3*>(_q1 + colA);      \
            const F3 _pb = *reinterpret_cast<const F3*>(_q2 + colA);      \
            A0 = _pa.x; A1 = _pa.y; A2 = _pa.z;                           \
            B0 = _pb.x; B1 = _pb.y; B2 = _pb.z;                           \
            if (halo) {                                                   \
                const F3 _pc = *reinterpret_cast<const F3*>(_q1 + colB);  \
                const F3 _pd = *reinterpret_cast<const F3*>(_q2 + colB);  \
                C0  = _pc.x; C1v = _pc.y; C2v = _pc.z;                    \
                D0  = _pd.x; D1  = _pd.y; D2  = _pd.z;                    \
            }                                                             \
        }                                                                 \
    }

// Convert current raw regs (row IY) to lumas a,c then pack (s,d)=(a+c,a-c)
// into ONE float2 per column (single volatile ds_write_b64). Parity IY&1.
#define STORE_ROW(IY)                                                     \
    {                                                                     \
        volatile v2f* const _sp = ((IY) & 1) ? sb1 : sb0;                 \
        {                                                                 \
            const float _a = luma3(cA0, cA1, cA2);                        \
            const float _c = luma3(cB0, cB1, cB2);                        \
            v2f _v; _v.x = _a + _c; _v.y = _a - _c;                       \
            _sp[lane] = _v;                                               \
        }                                                                 \
        if (lane < 10) {                                                  \
            const float _a = luma3(cC0, cC1, cC2);                        \
            const float _c = luma3(cD0, cD1, cD2);                        \
            v2f _v; _v.x = _a + _c; _v.y = _a - _c;                       \
            _sp[64 + lane] = _v;                                          \
        }                                                                 \
    }

#define ROTATE_RAW()                                                      \
    {                                                                     \
        cA0 = nA0; cA1 = nA1; cA2 = nA2; cB0 = nB0; cB1 = nB1; cB2 = nB2; \
        cC0 = nC0; cC1 = nC1; cC2 = nC2; cD0 = nD0; cD1 = nD1; cD2 = nD2; \
    }

// One row step: prefetch raw row IY+2; convert+store row IY+1; h-conv row
// IY from LDS into packed pairs HSD=(S,D), HQD=(Q2,D2). All DS ops are
// volatile -> program order among them is preserved (write row IY+1
// before any next-step read; reads of parity q before the step-(IY+2)
// write of parity q). Global loads are free to float across steps.
// h-conv tap = 1x ds_read_b64 + 3 packed-f32 ops (pk_fma/pk_mul).
#define ROW_STEP(IY, HSD, HQD)                                            \
    {                                                                     \
        LOAD_RAW((IY) + 2, nA0,nA1,nA2, nB0,nB1,nB2,                      \
                           nC0,nC1,nC2, nD0,nD1,nD2);                     \
        STORE_ROW((IY) + 1);                                              \
        ROTATE_RAW();                                                     \
        {                                                                 \
            volatile v2f* const _sr = ((IY) & 1) ? sb1 : sb0;             \
            v2f _hm = {0.f, 0.f}, _hq = {0.f, 0.f};                       \
            _Pragma("unroll")                                             \
            for (int _k = 0; _k < WS; ++_k) {                             \
                const float _gk = wv.g[_k];                               \
                const v2f _gv = {_gk, _gk};                               \
                const v2f _pv = _sr[lane + _k];                           \
                _hm = __builtin_elementwise_fma(_gv, _pv, _hm);           \
                const v2f _tv = _pv * _pv;                                \
                _hq = __builtin_elementwise_fma(_gv, _tv, _hq);           \
            }                                                             \
            HSD = _hm; HQD = _hq;                                         \
        }                                                                 \
    }

    // Register ring: slot s holds packed h-conv pairs of input row r with
    // r % 11 == s. Zero-init ALL slots — no undef values anywhere, ever.
    v2f rSD[WS], rQD[WS];
    #pragma unroll
    for (int s = 0; s < WS; ++s) {
        rSD[s] = (v2f){0.f, 0.f}; rQD[s] = (v2f){0.f, 0.f};
    }

    // Prologue: raw row 0 -> c; raw row 1 -> n (in flight); row 0 -> LDS.
    LOAD_RAW(0, cA0,cA1,cA2, cB0,cB1,cB2, cC0,cC1,cC2, cD0,cD1,cD2);
    LOAD_RAW(1, nA0,nA1,nA2, nB0,nB1,nB2, nC0,nC1,nC2, nD0,nD1,nD2);
    STORE_ROW(0);                       // one-time stall on row-0 loads
    ROTATE_RAW();                       // c = raw row 1

    // Fill ring with input rows 0..9 (slots 0..9).
    #pragma unroll
    for (int j = 0; j < 10; ++j)
        ROW_STEP(j, rSD[j], rQD[j]);

    float local = 0.f;

// Output row OY (JM == OY % 11, compile-time): insert row OY+10 at slot
// (JM+10)%11, then packed vertical 11-tap conv over slots (JM+k)%11,
// unpack via the (s,d) algebra, and SSIM.
#define DO_ROW(OY, JM)                                                    \
    {                                                                     \
        ROW_STEP((OY) + 10,                                               \
                 rSD[((JM) + 10) % WS], rQD[((JM) + 10) % WS]);           \
        v2f _MU = {0.f, 0.f}, _EX = {0.f, 0.f};                           \
        _Pragma("unroll")                                                 \
        for (int _k = 0; _k < WS; ++_k) {                                 \
            const float _gk = wv.g[_k];                                   \
            const v2f _gv = {_gk, _gk};                                   \
            const int _s = ((JM) + _k) % WS;                              \
            _MU = __builtin_elementwise_fma(_gv, rSD[_s], _MU);           \
            _EX = __builtin_elementwise_fma(_gv, rQD[_s], _EX);           \
        }                                                                 \
        if (colok && (r0 + (OY)) < OUTD) {                                \
            const float _mu1 = 0.5f * (_MU.x + _MU.y);                    \
            const float _mu2 = 0.5f * (_MU.x - _MU.y);                    \
            const float _eq  = 0.5f  * (_EX.x + _EX.y);                   \
            const float _ex  = 0.25f * (_EX.x - _EX.y);                   \
            const float _m1s = _mu1 * _mu1;                               \
            const float _m2s = _mu2 * _mu2;                               \
            const float _m12 = _mu1 * _mu2;                               \
            const float _num = (2.f * _m12 + C1F) *                       \
                               (2.f * (_ex - _m12) + C2F);                \
            const float _den = (_m1s + _m2s + C1F) *                      \
                               ((_eq - _m1s - _m2s) + C2F);               \
            local = fmaf(_num, __builtin_amdgcn_rcpf(_den), local);       \
        }                                                                 \
    }

    // Output rows 0..21: ROLLED 2-chunk loop; rows 22..31 unrolled tail.
    // Ring indices stay compile-time (JM=j).
    #pragma unroll 1
    for (int c = 0; c < 2; ++c) {
        const int base = c * 11;
        #pragma unroll
        for (int j = 0; j < 11; ++j)
            DO_ROW(base + j, j);
    }
    #pragma unroll
    for (int j = 0; j < 10; ++j)
        DO_ROW(22 + j, j);

    // Block reduction: wave shuffle (f32 tree) -> LDS (double) -> one atomic.
    for (int off = 32; off > 0; off >>= 1)
        local += __shfl_down(local, off, 64);
    if (lane == 0) wsum[wvid] = (double)local;
    __syncthreads();
    if (t == 0) {
        const double s = wsum[0] + wsum[1] + wsum[2] + wsum[3];
        atomicAdd(acc_out, s);
    }
}

__global__ void ssim_finalize_kernel(const double* __restrict__ acc,
                                     float* __restrict__ out)
{
    out[0] = (float)(acc[0] / N_OUT_TOTAL);
}

extern "C" void kernel_launch(void* const* d_in, const int* in_sizes, int n_in,
                              void* d_out, int out_size, void* d_ws, size_t ws_size,
                              hipStream_t stream) {
    const float* img1 = (const float*)d_in[0];
    const float* img2 = (const float*)d_in[1];
    float* out = (float*)d_out;
    double* acc = (double*)d_ws;

    // Gaussian window, computed exactly as the numpy reference (float32 ops)
    GW w;
    {
        float g[WS];
        float s = 0.f;
        for (int i = 0; i < WS; ++i) {
            const float x = (float)(i - WS / 2);
            g[i] = expf(-(x * x) / (2.f * 1.5f * 1.5f));
            s += g[i];
        }
        for (int i = 0; i < WS; ++i) w.g[i] = g[i] / s;
    }

    hipMemsetAsync(d_ws, 0, sizeof(double), stream);

    dim3 grid(2, (OUTD + STRIP - 1) / STRIP, BATCH);   // 2 x 16 x 32 = 1024 blocks
    ssim_stream_kernel<<<grid, 256, 0, stream>>>(img1, img2, acc, w);
    ssim_finalize_kernel<<<1, 1, 0, stream>>>(acc, out);
}